// Round 1
// baseline (19933.090 us; speedup 1.0000x reference)
//
#include <hip/hip_runtime.h>
#include <hip/hip_bf16.h>
#include <math.h>

// Elman RNN: out[b][t][j] = H_t, H_t = tanh(X_t @ W_xh + H_{t-1} @ W_hh + b)
// Phase 1: proj_gemm writes Xp = X@W_xh + b into d_out's [B,S,H] region.
// Phase 2: 1024x rnn_step kernels update d_out in place: H_t over Xp_t.

#define B_SZ 32
#define S_SZ 1024
#define H_SZ 1024
#define K_SZ 1024

// ---------------- Phase 1: input projection GEMM (fp32) ----------------
// C[M,N] = A[M,K] @ B[K,N] + bias;  M=32768, N=K=1024.
// 128x128 block tile, BK=8, 256 threads, 8x8 micro-tile per thread.
#define BM 128
#define BN 128
#define BK 8

__global__ __launch_bounds__(256) void proj_gemm(
    const float* __restrict__ A,     // X   [M,K]
    const float* __restrict__ Bm,    // W_xh[K,N]
    const float* __restrict__ bias,  // [N]
    float* __restrict__ C,           // [M,N] (d_out Xp region)
    int M, int N, int K)
{
    __shared__ float As[BK][BM];   // stored transposed: As[k][m]
    __shared__ float Bs[BK][BN];

    const int tid  = threadIdx.x;
    const int row0 = blockIdx.y * BM;
    const int col0 = blockIdx.x * BN;
    const int tx = tid & 15;        // 0..15
    const int ty = tid >> 4;        // 0..15
    const int mBase = ty * 8;
    const int nBase = tx * 8;

    float acc[8][8];
    #pragma unroll
    for (int i = 0; i < 8; ++i)
        #pragma unroll
        for (int j = 0; j < 8; ++j) acc[i][j] = 0.f;

    for (int k0 = 0; k0 < K; k0 += BK) {
        // A tile: 128 rows x 8 k -> 256 float4 along k (one per thread)
        {
            const int r  = tid >> 1;          // 0..127
            const int kq = (tid & 1) * 4;     // 0 or 4
            const float4 av = *(const float4*)(&A[(size_t)(row0 + r) * K + k0 + kq]);
            As[kq + 0][r] = av.x;
            As[kq + 1][r] = av.y;
            As[kq + 2][r] = av.z;
            As[kq + 3][r] = av.w;
            // B tile: 8 rows x 128 cols -> 256 float4 (one per thread)
            const int kr = tid >> 5;          // 0..7
            const int cq = (tid & 31) * 4;    // 0..124
            *(float4*)(&Bs[kr][cq]) =
                *(const float4*)(&Bm[(size_t)(k0 + kr) * N + col0 + cq]);
        }
        __syncthreads();

        #pragma unroll
        for (int kk = 0; kk < BK; ++kk) {
            float a[8], b[8];
            *(float4*)&a[0] = *(const float4*)&As[kk][mBase];
            *(float4*)&a[4] = *(const float4*)&As[kk][mBase + 4];
            *(float4*)&b[0] = *(const float4*)&Bs[kk][nBase];
            *(float4*)&b[4] = *(const float4*)&Bs[kk][nBase + 4];
            #pragma unroll
            for (int i = 0; i < 8; ++i)
                #pragma unroll
                for (int j = 0; j < 8; ++j)
                    acc[i][j] += a[i] * b[j];
        }
        __syncthreads();
    }

    // epilogue: add bias, store
    #pragma unroll
    for (int i = 0; i < 8; ++i) {
        const int r = row0 + mBase + i;
        #pragma unroll
        for (int jq = 0; jq < 8; jq += 4) {
            const int c = col0 + nBase + jq;
            const float4 bv = *(const float4*)(&bias[c]);
            float4 o;
            o.x = acc[i][jq + 0] + bv.x;
            o.y = acc[i][jq + 1] + bv.y;
            o.z = acc[i][jq + 2] + bv.z;
            o.w = acc[i][jq + 3] + bv.w;
            *(float4*)(&C[(size_t)r * N + c]) = o;
        }
    }
}

// ---------------- Phase 2: one recurrence step ----------------
// 256 blocks x 256 threads. Block = (batchgroup = blockIdx>>5 [8 groups of 4
// batches], colgroup = blockIdx&31 [32 cols each]).
// Thread: j = tid&31 (lane 0..31 -> coalesced 128B W rows),
//         khalf = (tid>>5)&1 (K split in two, reduced via shfl_xor 32),
//         wave = tid>>6 -> batch within group (H reads are wave-broadcast).
__global__ __launch_bounds__(256) void rnn_step(
    float* __restrict__ HS,        // d_out base [B][S][H]; Xp in, H out (in place)
    const float* __restrict__ W,   // W_hh [K][H] (k-major)
    float* __restrict__ Hlast,     // d_out + B*S*H
    int t)
{
    const int tid   = threadIdx.x;
    const int j     = (blockIdx.x & 31) * 32 + (tid & 31);
    const int khalf = (tid >> 5) & 1;
    const int b     = ((blockIdx.x >> 5) << 2) + (tid >> 6);

    float acc = 0.f;
    if (t > 0) {
        const float* __restrict__ h = &HS[((size_t)b * S_SZ + (t - 1)) * H_SZ];
        const int k0 = khalf * 512;
        const float* __restrict__ wp = &W[(size_t)k0 * H_SZ + j];
        #pragma unroll 2
        for (int k = 0; k < 512; k += 4) {
            const float4 hv = *(const float4*)(&h[k0 + k]);
            acc += hv.x * wp[(size_t)(k + 0) * H_SZ];
            acc += hv.y * wp[(size_t)(k + 1) * H_SZ];
            acc += hv.z * wp[(size_t)(k + 2) * H_SZ];
            acc += hv.w * wp[(size_t)(k + 3) * H_SZ];
        }
    }
    acc += __shfl_xor(acc, 32);   // combine the two K halves (same wave)

    if (khalf == 0) {
        const size_t idx = ((size_t)b * S_SZ + t) * H_SZ + j;
        const float v = tanhf(HS[idx] + acc);
        HS[idx] = v;
        if (t == S_SZ - 1) Hlast[(size_t)b * H_SZ + j] = v;
    }
}

extern "C" void kernel_launch(void* const* d_in, const int* in_sizes, int n_in,
                              void* d_out, int out_size, void* d_ws, size_t ws_size,
                              hipStream_t stream) {
    const float* X    = (const float*)d_in[0];  // [B,S,K]
    const float* W_xh = (const float*)d_in[1];  // [K,H]
    const float* W_hh = (const float*)d_in[2];  // [H,H]
    const float* b_h  = (const float*)d_in[3];  // [H]
    float* out = (float*)d_out;
    float* Hlast = out + (size_t)B_SZ * S_SZ * H_SZ;

    // Phase 1: Xp = X @ W_xh + b into d_out's [B,S,H] region.
    dim3 gridA(H_SZ / BN, (B_SZ * S_SZ) / BM);
    proj_gemm<<<gridA, 256, 0, stream>>>(X, W_xh, b_h, out,
                                         B_SZ * S_SZ, H_SZ, K_SZ);

    // Phase 2: sequential recurrence, one kernel per timestep.
    for (int t = 0; t < S_SZ; ++t) {
        rnn_step<<<256, 256, 0, stream>>>(out, W_hh, Hlast, t);
    }
}

// Round 3
// 11999.704 us; speedup vs baseline: 1.6611x; 1.6611x over previous
//
#include <hip/hip_runtime.h>
#include <hip/hip_bf16.h>
#include <math.h>

// Elman RNN: out[b][t][j] = H_t, H_t = tanh(X_t @ W_xh + H_{t-1} @ W_hh + b)
// Phase 1: proj_gemm writes Xp = X@W_xh + b into d_out's [B,S,H] region.
// Phase 2: ONE persistent kernel runs all 1024 steps. W_hh strip in registers
//          (64 VGPR/thread), H broadcast via L3 + per-(group,t) flag sync.

#define B_SZ 32
#define S_SZ 1024
#define H_SZ 1024
#define K_SZ 1024

// ---------------- Phase 1: input projection GEMM (fp32) ----------------
#define BM 128
#define BN 128
#define BK 8

__global__ __launch_bounds__(256) void proj_gemm(
    const float* __restrict__ A,     // X   [M,K]
    const float* __restrict__ Bm,    // W_xh[K,N]
    const float* __restrict__ bias,  // [N]
    float* __restrict__ C,           // [M,N] (d_out Xp region)
    int M, int N, int K)
{
    __shared__ float As[BK][BM];   // transposed: As[k][m]
    __shared__ float Bs[BK][BN];

    const int tid  = threadIdx.x;
    const int row0 = blockIdx.y * BM;
    const int col0 = blockIdx.x * BN;
    const int tx = tid & 15;
    const int ty = tid >> 4;
    const int mBase = ty * 8;
    const int nBase = tx * 8;

    float acc[8][8];
    #pragma unroll
    for (int i = 0; i < 8; ++i)
        #pragma unroll
        for (int j = 0; j < 8; ++j) acc[i][j] = 0.f;

    for (int k0 = 0; k0 < K; k0 += BK) {
        {
            const int r  = tid >> 1;
            const int kq = (tid & 1) * 4;
            const float4 av = *(const float4*)(&A[(size_t)(row0 + r) * K + k0 + kq]);
            As[kq + 0][r] = av.x;
            As[kq + 1][r] = av.y;
            As[kq + 2][r] = av.z;
            As[kq + 3][r] = av.w;
            const int kr = tid >> 5;
            const int cq = (tid & 31) * 4;
            *(float4*)(&Bs[kr][cq]) =
                *(const float4*)(&Bm[(size_t)(k0 + kr) * N + col0 + cq]);
        }
        __syncthreads();

        #pragma unroll
        for (int kk = 0; kk < BK; ++kk) {
            float a[8], b[8];
            *(float4*)&a[0] = *(const float4*)&As[kk][mBase];
            *(float4*)&a[4] = *(const float4*)&As[kk][mBase + 4];
            *(float4*)&b[0] = *(const float4*)&Bs[kk][nBase];
            *(float4*)&b[4] = *(const float4*)&Bs[kk][nBase + 4];
            #pragma unroll
            for (int i = 0; i < 8; ++i)
                #pragma unroll
                for (int j = 0; j < 8; ++j)
                    acc[i][j] += a[i] * b[j];
        }
        __syncthreads();
    }

    #pragma unroll
    for (int i = 0; i < 8; ++i) {
        const int r = row0 + mBase + i;
        #pragma unroll
        for (int jq = 0; jq < 8; jq += 4) {
            const int c = col0 + nBase + jq;
            const float4 bv = *(const float4*)(&bias[c]);
            float4 o;
            o.x = acc[i][jq + 0] + bv.x;
            o.y = acc[i][jq + 1] + bv.y;
            o.z = acc[i][jq + 2] + bv.z;
            o.w = acc[i][jq + 3] + bv.w;
            *(float4*)(&C[(size_t)r * N + c]) = o;
        }
    }
}

// ---------------- init: zero the sync counters in d_ws ----------------
__global__ void init_cnt(unsigned int* __restrict__ cnt, int n) {
    int i = blockIdx.x * 256 + threadIdx.x;
    if (i < n) cnt[i] = 0u;
}

// ---------------- Phase 2: persistent recurrence kernel ----------------
// 256 blocks x 512 threads, 1 block/CU (co-resident: 256 blocks <= 256 CUs).
// Block (g = blockIdx&7, c = blockIdx>>3): batches [4g,4g+4), cols [32c,32c+32).
// Thread (j = tid&31 -> col, seg = tid>>5 in [0,16) -> k range [64*seg,+64)).
// W strip held in registers: w[64] = W_hh[64*seg + i][32c + j].
// Per-step sync: cnt[g][t] arrival counters (32 producers per (g,t)).
__global__ __launch_bounds__(512, 2) void rnn_persist(
    float* __restrict__ HS,        // d_out [B][S][H]; Xp in, H out (in place)
    const float* __restrict__ W,   // W_hh [K][H]
    float* __restrict__ Hlast,     // d_out + B*S*H
    unsigned int* __restrict__ cnt // [8][S_SZ]
    )
{
    const int g    = blockIdx.x & 7;
    const int c    = blockIdx.x >> 3;
    const int col0 = c * 32;
    const int b0   = g * 4;
    const int tid  = threadIdx.x;
    const int j    = tid & 31;
    const int seg  = tid >> 5;          // 0..15

    __shared__ __align__(16) float Hs[4][1024];     // H_{t-1} for 4 batches
    __shared__ float red[8][4][32];                 // per-wave partials

    // Load W strip into registers (once).
    float w[64];
    {
        const float* wp = W + (size_t)(seg * 64) * H_SZ + col0 + j;
        #pragma unroll
        for (int i = 0; i < 64; ++i) w[i] = wp[(size_t)i * H_SZ];
    }

    unsigned int* flag = cnt + g * S_SZ;

    for (int t = 0; t < S_SZ; ++t) {
        if (t > 0) {
            // ---- wait for H_{t-1} of this batch group ----
            if (tid == 0) {
                while (__hip_atomic_load(flag + (t - 1), __ATOMIC_RELAXED,
                                         __HIP_MEMORY_SCOPE_AGENT) < 32u) {
                    __builtin_amdgcn_s_sleep(2);
                }
                __threadfence();   // acquire: invalidate stale L1/L2 lines
            }
            __syncthreads();

            // ---- stage H_{t-1}[b0..b0+3][:] into LDS (16 KB) ----
            #pragma unroll
            for (int ch = 0; ch < 2; ++ch) {
                const int f4 = tid + ch * 512;        // [0,1024) float4 slots
                const int b  = f4 >> 8;
                const int k4 = f4 & 255;
                const float4* src = (const float4*)
                    (&HS[((size_t)(b0 + b) * S_SZ + (t - 1)) * H_SZ]);
                *(float4*)(&Hs[b][k4 * 4]) = src[k4];
            }
            __syncthreads();

            // ---- MAC: acc[b] = sum_{k in seg range} H[b][k] * W[k][j] ----
            float acc[4];
            #pragma unroll
            for (int b = 0; b < 4; ++b) {
                const float4* hb = (const float4*)(&Hs[b][seg * 64]);
                float a = 0.f;
                #pragma unroll
                for (int q = 0; q < 16; ++q) {
                    const float4 h = hb[q];   // broadcast across 32 j-lanes
                    a += h.x * w[4 * q + 0];
                    a += h.y * w[4 * q + 1];
                    a += h.z * w[4 * q + 2];
                    a += h.w * w[4 * q + 3];
                }
                acc[b] = a;
            }
            // combine the two k-halves within the wave (seg ^ 1)
            #pragma unroll
            for (int b = 0; b < 4; ++b) acc[b] += __shfl_xor(acc[b], 32);
            const int wv = tid >> 6;
            if ((tid & 63) < 32) {
                #pragma unroll
                for (int b = 0; b < 4; ++b) red[wv][b][j] = acc[b];
            }
            __syncthreads();
        }

        // ---- epilogue: first 128 threads own the 4b x 32j outputs ----
        if (tid < 128) {
            const int b  = tid >> 5;
            const int jj = tid & 31;
            float s = 0.f;
            if (t > 0) {
                #pragma unroll
                for (int wv2 = 0; wv2 < 8; ++wv2) s += red[wv2][b][jj];
            }
            const size_t idx = ((size_t)(b0 + b) * S_SZ + t) * H_SZ + col0 + jj;
            const float v = tanhf(HS[idx] + s);   // HS[idx] = Xp[b][t][j]
            HS[idx] = v;
            if (t == S_SZ - 1)
                Hlast[(size_t)(b0 + b) * H_SZ + col0 + jj] = v;
        }

        // ---- publish: drain stores, flush to L3, arrive ----
        __syncthreads();           // per-wave vmcnt(0) before barrier
        if (tid == 0) {
            __threadfence();       // release: writeback dirty L2 -> L3
            __hip_atomic_fetch_add(flag + t, 1u, __ATOMIC_RELAXED,
                                   __HIP_MEMORY_SCOPE_AGENT);
        }
    }
}

extern "C" void kernel_launch(void* const* d_in, const int* in_sizes, int n_in,
                              void* d_out, int out_size, void* d_ws, size_t ws_size,
                              hipStream_t stream) {
    const float* X    = (const float*)d_in[0];  // [B,S,K]
    const float* W_xh = (const float*)d_in[1];  // [K,H]
    const float* W_hh = (const float*)d_in[2];  // [H,H]
    const float* b_h  = (const float*)d_in[3];  // [H]
    float* out = (float*)d_out;
    float* Hlast = out + (size_t)B_SZ * S_SZ * H_SZ;
    unsigned int* cnt = (unsigned int*)d_ws;    // [8][S_SZ] counters

    // zero sync counters (d_ws is re-poisoned before every launch)
    init_cnt<<<(8 * S_SZ + 255) / 256, 256, 0, stream>>>(cnt, 8 * S_SZ);

    // Phase 1: Xp = X @ W_xh + b into d_out's [B,S,H] region.
    dim3 gridA(H_SZ / BN, (B_SZ * S_SZ) / BM);
    proj_gemm<<<gridA, 256, 0, stream>>>(X, W_xh, b_h, out,
                                         B_SZ * S_SZ, H_SZ, K_SZ);

    // Phase 2: all 1024 recurrence steps in one persistent kernel.
    rnn_persist<<<256, 512, 0, stream>>>(out, W_hh, Hlast, cnt);
}

// Round 4
// 4766.561 us; speedup vs baseline: 4.1819x; 2.5175x over previous
//
#include <hip/hip_runtime.h>
#include <hip/hip_bf16.h>
#include <math.h>

// Elman RNN: out[b][t][j] = H_t, H_t = tanh(X_t @ W_xh + H_{t-1} @ W_hh + b)
// Phase 1: proj_gemm writes Xp = X@W_xh + b into d_out's [B,S,H] region.
// Phase 2: ONE persistent kernel runs all 1024 steps.
//   - W_hh strip pinned in 64 VGPRs via asm (round-3 failure: fences made the
//     compiler re-load W every step; VGPR_Count was 52).
//   - Cross-block H exchange via agent-scope RELAXED atomics (cache-bypassing,
//     complete at L3 which is coherent across XCDs). NO __threadfence: round-3
//     failure was 64 full-L2 wbl2/inv walks per XCD per step (~10 us/step).
//     Visibility: __syncthreads emits s_waitcnt vmcnt(0) before s_barrier, so
//     all atomic H stores are agent-visible before the flag atomicAdd.

#define B_SZ 32
#define S_SZ 1024
#define H_SZ 1024
#define K_SZ 1024

// ---------------- Phase 1: input projection GEMM (fp32) ----------------
#define BM 128
#define BN 128
#define BK 8

__global__ __launch_bounds__(256) void proj_gemm(
    const float* __restrict__ A,     // X   [M,K]
    const float* __restrict__ Bm,    // W_xh[K,N]
    const float* __restrict__ bias,  // [N]
    float* __restrict__ C,           // [M,N] (d_out Xp region)
    int M, int N, int K)
{
    __shared__ float As[BK][BM];   // transposed: As[k][m]
    __shared__ float Bs[BK][BN];

    const int tid  = threadIdx.x;
    const int row0 = blockIdx.y * BM;
    const int col0 = blockIdx.x * BN;
    const int tx = tid & 15;
    const int ty = tid >> 4;
    const int mBase = ty * 8;
    const int nBase = tx * 8;

    float acc[8][8];
    #pragma unroll
    for (int i = 0; i < 8; ++i)
        #pragma unroll
        for (int j = 0; j < 8; ++j) acc[i][j] = 0.f;

    for (int k0 = 0; k0 < K; k0 += BK) {
        {
            const int r  = tid >> 1;
            const int kq = (tid & 1) * 4;
            const float4 av = *(const float4*)(&A[(size_t)(row0 + r) * K + k0 + kq]);
            As[kq + 0][r] = av.x;
            As[kq + 1][r] = av.y;
            As[kq + 2][r] = av.z;
            As[kq + 3][r] = av.w;
            const int kr = tid >> 5;
            const int cq = (tid & 31) * 4;
            *(float4*)(&Bs[kr][cq]) =
                *(const float4*)(&Bm[(size_t)(k0 + kr) * N + col0 + cq]);
        }
        __syncthreads();

        #pragma unroll
        for (int kk = 0; kk < BK; ++kk) {
            float a[8], b[8];
            *(float4*)&a[0] = *(const float4*)&As[kk][mBase];
            *(float4*)&a[4] = *(const float4*)&As[kk][mBase + 4];
            *(float4*)&b[0] = *(const float4*)&Bs[kk][nBase];
            *(float4*)&b[4] = *(const float4*)&Bs[kk][nBase + 4];
            #pragma unroll
            for (int i = 0; i < 8; ++i)
                #pragma unroll
                for (int j = 0; j < 8; ++j)
                    acc[i][j] += a[i] * b[j];
        }
        __syncthreads();
    }

    #pragma unroll
    for (int i = 0; i < 8; ++i) {
        const int r = row0 + mBase + i;
        #pragma unroll
        for (int jq = 0; jq < 8; jq += 4) {
            const int c = col0 + nBase + jq;
            const float4 bv = *(const float4*)(&bias[c]);
            float4 o;
            o.x = acc[i][jq + 0] + bv.x;
            o.y = acc[i][jq + 1] + bv.y;
            o.z = acc[i][jq + 2] + bv.z;
            o.w = acc[i][jq + 3] + bv.w;
            *(float4*)(&C[(size_t)r * N + c]) = o;
        }
    }
}

// ---------------- init: zero the sync counters in d_ws ----------------
__global__ void init_cnt(unsigned int* __restrict__ cnt, int n) {
    int i = blockIdx.x * 256 + threadIdx.x;
    if (i < n) cnt[i] = 0u;
}

// ---------------- Phase 2: persistent recurrence kernel ----------------
// 256 blocks x 512 threads, 1 block/CU.
// Block (g = blockIdx&7, c = blockIdx>>3): batches [4g,4g+4), cols [32c,32c+32).
// Thread (j = tid&31 -> col, seg = tid>>5 in [0,16) -> k range [64*seg,+64)).
// W strip in registers: w[64] = W_hh[64*seg + i][32c + j], asm-pinned.
// Per-step sync: cnt[g][t] arrival counters (32 producers per (g,t)).
// ALL cross-block H traffic uses agent-scope relaxed atomics (L3-coherent).
__global__ __launch_bounds__(512, 2) void rnn_persist(
    float* __restrict__ HS,        // d_out [B][S][H]; Xp in, H out (in place)
    const float* __restrict__ W,   // W_hh [K][H]
    float* __restrict__ Hlast,     // d_out + B*S*H
    unsigned int* __restrict__ cnt // [8][S_SZ]
    )
{
    const int g    = blockIdx.x & 7;
    const int c    = blockIdx.x >> 3;
    const int col0 = c * 32;
    const int b0   = g * 4;
    const int tid  = threadIdx.x;
    const int j    = tid & 31;
    const int seg  = tid >> 5;          // 0..15

    __shared__ __align__(16) float Hs[4][1024];     // H_{t-1} for 4 batches
    __shared__ float red[8][4][32];                 // per-wave partials

    // Load W strip into registers (once), then pin: the asm makes the values
    // opaque so the compiler cannot sink/rematerialize the loads into the
    // t-loop (round-3 bug: VGPR_Count=52 => W re-loaded every step).
    float w[64];
    {
        const float* wp = W + (size_t)(seg * 64) * H_SZ + col0 + j;
        #pragma unroll
        for (int i = 0; i < 64; ++i) w[i] = wp[(size_t)i * H_SZ];
        #pragma unroll
        for (int i = 0; i < 64; ++i) asm volatile("" : "+v"(w[i]));
    }

    unsigned int* flag = cnt + g * S_SZ;

    for (int t = 0; t < S_SZ; ++t) {
        if (t > 0) {
            // ---- wait for H_{t-1} of this batch group (relaxed poll) ----
            if (tid == 0) {
                while (__hip_atomic_load(flag + (t - 1), __ATOMIC_RELAXED,
                                         __HIP_MEMORY_SCOPE_AGENT) < 32u) {
                    __builtin_amdgcn_s_sleep(2);
                }
            }
            __syncthreads();

            // ---- stage H_{t-1}[b0..b0+3][:] into LDS (16 KB) via 8-byte
            //      agent atomic loads (bypass L1/L2, read L3-fresh) ----
            #pragma unroll
            for (int ch = 0; ch < 4; ++ch) {
                const int f8 = tid + ch * 512;        // [0,2048) qword slots
                const int b  = f8 >> 9;               // 512 qwords per batch
                const int qw = f8 & 511;
                const unsigned long long* src = (const unsigned long long*)
                    (&HS[((size_t)(b0 + b) * S_SZ + (t - 1)) * H_SZ]);
                const unsigned long long v8 = __hip_atomic_load(
                    &src[qw], __ATOMIC_RELAXED, __HIP_MEMORY_SCOPE_AGENT);
                *(unsigned long long*)(&Hs[b][qw * 2]) = v8;
            }
            __syncthreads();

            // ---- MAC: acc[b] = sum_{k in seg range} H[b][k] * W[k][j] ----
            float acc[4];
            #pragma unroll
            for (int b = 0; b < 4; ++b) {
                const float4* hb = (const float4*)(&Hs[b][seg * 64]);
                float a = 0.f;
                #pragma unroll
                for (int q = 0; q < 16; ++q) {
                    const float4 h = hb[q];   // broadcast across 32 j-lanes
                    a += h.x * w[4 * q + 0];
                    a += h.y * w[4 * q + 1];
                    a += h.z * w[4 * q + 2];
                    a += h.w * w[4 * q + 3];
                }
                acc[b] = a;
            }
            // combine the two k-halves within the wave (seg ^ 1)
            #pragma unroll
            for (int b = 0; b < 4; ++b) acc[b] += __shfl_xor(acc[b], 32);
            const int wv = tid >> 6;
            if ((tid & 63) < 32) {
                #pragma unroll
                for (int b = 0; b < 4; ++b) red[wv][b][j] = acc[b];
            }
            __syncthreads();
        }

        // ---- epilogue: first 128 threads own the 4b x 32j outputs ----
        if (tid < 128) {
            const int b  = tid >> 5;
            const int jj = tid & 31;
            float s = 0.f;
            if (t > 0) {
                #pragma unroll
                for (int wv2 = 0; wv2 < 8; ++wv2) s += red[wv2][b][jj];
            }
            const size_t idx = ((size_t)(b0 + b) * S_SZ + t) * H_SZ + col0 + jj;
            const float v = tanhf(HS[idx] + s);   // HS[idx] = Xp[b][t][j]
            // publish H_t at the agent coherent point (no fence needed)
            __hip_atomic_store(&HS[idx], v, __ATOMIC_RELAXED,
                               __HIP_MEMORY_SCOPE_AGENT);
            if (t == S_SZ - 1)
                Hlast[(size_t)(b0 + b) * H_SZ + col0 + jj] = v;
        }

        // __syncthreads: compiler emits s_waitcnt vmcnt(0) before s_barrier,
        // so all atomic H stores above are agent-visible before we arrive.
        __syncthreads();
        if (tid == 0) {
            __hip_atomic_fetch_add(flag + t, 1u, __ATOMIC_RELAXED,
                                   __HIP_MEMORY_SCOPE_AGENT);
        }
    }
}

extern "C" void kernel_launch(void* const* d_in, const int* in_sizes, int n_in,
                              void* d_out, int out_size, void* d_ws, size_t ws_size,
                              hipStream_t stream) {
    const float* X    = (const float*)d_in[0];  // [B,S,K]
    const float* W_xh = (const float*)d_in[1];  // [K,H]
    const float* W_hh = (const float*)d_in[2];  // [H,H]
    const float* b_h  = (const float*)d_in[3];  // [H]
    float* out = (float*)d_out;
    float* Hlast = out + (size_t)B_SZ * S_SZ * H_SZ;
    unsigned int* cnt = (unsigned int*)d_ws;    // [8][S_SZ] counters

    // zero sync counters (d_ws is re-poisoned before every launch)
    init_cnt<<<(8 * S_SZ + 255) / 256, 256, 0, stream>>>(cnt, 8 * S_SZ);

    // Phase 1: Xp = X @ W_xh + b into d_out's [B,S,H] region.
    dim3 gridA(H_SZ / BN, (B_SZ * S_SZ) / BM);
    proj_gemm<<<gridA, 256, 0, stream>>>(X, W_xh, b_h, out,
                                         B_SZ * S_SZ, H_SZ, K_SZ);

    // Phase 2: all 1024 recurrence steps in one persistent kernel.
    rnn_persist<<<256, 512, 0, stream>>>(out, W_hh, Hlast, cnt);
}